// Round 21
// baseline (312.094 us; speedup 1.0000x reference)
//
#include <hip/hip_runtime.h>

typedef unsigned short u16;
typedef float f32x4 __attribute__((ext_vector_type(4)));
typedef __bf16 bf16x8 __attribute__((ext_vector_type(8)));
typedef u16 u16x8 __attribute__((ext_vector_type(8)));

#define VMCNT(n) asm volatile("s_waitcnt vmcnt(" #n ")" ::: "memory")

static __device__ __forceinline__ u16 f2bf(float f) {
  union { float f; unsigned u; } v; v.f = f;
  unsigned r = v.u + 0x7fffu + ((v.u >> 16) & 1u);  // RNE
  return (u16)(r >> 16);
}
static __device__ __forceinline__ u16 f2bf_n(float f) {
  __bf16 h = (__bf16)f;          // native cvt (RNE)
  return __builtin_bit_cast(u16, h);
}
static __device__ __forceinline__ float bf2f(u16 x) {
  union { unsigned u; float f; } v; v.u = (unsigned)x << 16; return v.f;
}

static __device__ __forceinline__ f32x4 mfma16(u16x8 a, u16x8 b, f32x4 c) {
  return __builtin_amdgcn_mfma_f32_16x16x32_bf16(
      __builtin_bit_cast(bf16x8, a), __builtin_bit_cast(bf16x8, b), c, 0, 0, 0);
}

static __device__ __forceinline__ void load_lds16(const void* g, void* l) {
  __builtin_amdgcn_global_load_lds(
      (const __attribute__((address_space(1))) void*)g,
      (__attribute__((address_space(3))) void*)l, 16, 0, 0);
}

// ---------------- f32 -> bf16, GEMM-A pre-swizzled (chunk c of row r at c^(r&7)) ----
__global__ void cvt_f32_bf16_swz(const float* __restrict__ in, u16* __restrict__ out, int n8) {
  int i = blockIdx.x * blockDim.x + threadIdx.x;
  if (i >= n8) return;
  int row = i >> 9;
  int j = i & 511;
  int jp = (j & ~7) | ((j & 7) ^ (row & 7));
  const float* src = in + (size_t)i * 8;
  u16x8 o;
  #pragma unroll
  for (int e = 0; e < 8; e++) o[e] = f2bf(src[e]);
  *(u16x8*)(out + ((size_t)row << 12) + jp * 8) = o;
}

// ------- transpose + convert: W[K][N] f32 -> Wt[N][K] bf16, pre-swizzled rows -------
__global__ __launch_bounds__(256)
void transpose_cvt(const float* __restrict__ W, u16* __restrict__ Wt, int K, int N) {
  __shared__ float tile[128][33];
  const int k0 = blockIdx.x * 128, n0 = blockIdx.y * 32;
  const int tr = threadIdx.x >> 3;         // 0..31
  const int tc4 = (threadIdx.x & 7) * 4;   // 0..28
  #pragma unroll
  for (int it = 0; it < 4; it++) {
    int kl = it * 32 + tr;
    float4 v = *(const float4*)&W[(size_t)(k0 + kl) * N + n0 + tc4];
    tile[kl][tc4] = v.x; tile[kl][tc4 + 1] = v.y;
    tile[kl][tc4 + 2] = v.z; tile[kl][tc4 + 3] = v.w;
  }
  __syncthreads();
  const int nl = threadIdx.x >> 4;         // 0..15
  const int dch = threadIdx.x & 15;        // dest 16B chunk 0..15
  #pragma unroll
  for (int it = 0; it < 2; it++) {
    int n = n0 + it * 16 + nl;
    int sch = (dch & 8) | ((dch & 7) ^ (n & 7));  // source chunk (involution)
    u16x8 o;
    #pragma unroll
    for (int e = 0; e < 8; e++) o[e] = f2bf(tile[sch * 8 + e][it * 16 + nl]);
    *(u16x8*)&Wt[(size_t)n * K + k0 + dch * 8] = o;
  }
}

// ---- merged Wk/Wv transpose (same math; one dispatch, branch on blockIdx.y) ----
__global__ __launch_bounds__(256)
void transpose_cvt2(const float* __restrict__ Wk, const float* __restrict__ Wv,
                    u16* __restrict__ Wkt, u16* __restrict__ Wvt, int K, int N) {
  __shared__ float tile[128][33];
  const int sel = blockIdx.y >= (unsigned)(N / 32);
  const int n0 = (blockIdx.y - (sel ? N / 32 : 0)) * 32;
  const float* W = sel ? Wv : Wk;
  u16* Wt = sel ? Wvt : Wkt;
  const int k0 = blockIdx.x * 128;
  const int tr = threadIdx.x >> 3;
  const int tc4 = (threadIdx.x & 7) * 4;
  #pragma unroll
  for (int it = 0; it < 4; it++) {
    int kl = it * 32 + tr;
    float4 v = *(const float4*)&W[(size_t)(k0 + kl) * N + n0 + tc4];
    tile[kl][tc4] = v.x; tile[kl][tc4 + 1] = v.y;
    tile[kl][tc4 + 2] = v.z; tile[kl][tc4 + 3] = v.w;
  }
  __syncthreads();
  const int nl = threadIdx.x >> 4;
  const int dch = threadIdx.x & 15;
  #pragma unroll
  for (int it = 0; it < 2; it++) {
    int n = n0 + it * 16 + nl;
    int sch = (dch & 8) | ((dch & 7) ^ (n & 7));
    u16x8 o;
    #pragma unroll
    for (int e = 0; e < 8; e++) o[e] = f2bf(tile[sch * 8 + e][it * 16 + nl]);
    *(u16x8*)&Wt[(size_t)n * K + k0 + dch * 8] = o;
  }
}

// ---------------- V transpose: qkv V cols -> vt[hk][d][s], chunk-swizzled ----------
__global__ __launch_bounds__(256)
void vtrans_k(const u16* __restrict__ qkv, u16* __restrict__ vt) {
  __shared__ u16 tile[32][33];
  int tx = threadIdx.x & 31, ty = threadIdx.x >> 5;
  int s0 = blockIdx.x * 32;
  int d0 = (blockIdx.y & 3) * 32;
  int hk = blockIdx.y >> 2;
  const u16* src = qkv + 5120 + (size_t)hk * 128;
  #pragma unroll
  for (int i = ty; i < 32; i += 8)
    tile[i][tx] = src[(size_t)(s0 + i) * 6144 + d0 + tx];
  __syncthreads();
  u16* dst = vt + (size_t)hk * 128 * 2048;
  #pragma unroll
  for (int i = ty; i < 32; i += 8) {
    int d = d0 + i;
    int s = s0 + tx;
    int sw = (s & ~63) | ((((s >> 3) & 7) ^ (d & 7)) << 3) | (s & 7);
    dst[(size_t)d * 2048 + sw] = tile[tx][i];
  }
}

// ---------------- RoPE cos/sin table: [L][64] float2 ----------------
__global__ void rope_table_k(float2* __restrict__ tab, const int* __restrict__ start, int L) {
  int i = blockIdx.x * blockDim.x + threadIdx.x;
  if (i >= L * 64) return;
  int p = i >> 6, j = i & 63;
  float inv = powf(10000.0f, -(float)j / 64.0f);
  float ang = (float)(p + start[0]) * inv;
  tab[i] = make_float2(cosf(ang), sinf(ang));
}

// ---------------- RoPE apply (bf16 in, strided) -> bf16 [L][H][128], * scale ----------
// (used for K only; Q-RoPE is fused into attn_k)
__global__ void rope_apply_b(const u16* __restrict__ in, int istride, int icol,
                             u16* __restrict__ outp, const float2* __restrict__ tab,
                             int total, int H, float scale, int swz) {
  int i = blockIdx.x * blockDim.x + threadIdx.x;  // total = L*H*8
  if (i >= total) return;
  int j8 = (i & 7) * 8;
  int h = (i >> 3) % H;
  int p = i / (8 * H);
  const u16* base = in + (size_t)p * istride + icol + h * 128;
  u16x8 a = *(const u16x8*)(base + j8);
  u16x8 b = *(const u16x8*)(base + j8 + 64);
  u16x8 o1, o2;
  #pragma unroll
  for (int e = 0; e < 8; e++) {
    float2 cs = tab[p * 64 + j8 + e];
    float av = bf2f(a[e]), bv = bf2f(b[e]);
    o1[e] = f2bf((av * cs.x - bv * cs.y) * scale);
    o2[e] = f2bf((av * cs.y + bv * cs.x) * scale);
  }
  int c1 = i & 7;
  int cs1 = swz ? (c1 ^ (p & 7)) : c1;
  u16* ob = outp + ((size_t)p * H + h) * 128 + cs1 * 8;
  *(u16x8*)ob = o1;
  *(u16x8*)(ob + 64) = o2;
}

// ======== 4-PHASE GEMM, 2 BLOCKS/CU: C = A[M][K] @ Bt[N][K]; BM=128, 256 thr ========
// Merges R20's (m,n2) quadrants into m-halves: 4 phases per 2 K-tiles (16 or 24
// MFMA/phase), B held fully in regs (bfull). Barriers/iter 16 -> 8, gates 8 -> 2.
// Sync residual (~40-45% of R20's 550cy phase) was the slack: LDS floor ~235cy,
// MFMA ~120cy.  Schedule per iter i (t0=2i in buf0, t1=2i+1 in buf1):
//   P0: read A[buf0]m0 + B[buf0]full; BURST-stage t1 -> buf1
//   P1: read A[buf0]m1;               gate VMCNT(0)  (P0 burst, age ~1.5 phases)
//   P2: read A[buf1]m0 + B[buf1]full; BURST-stage 2i+2 -> buf0 (if < NT)
//   P3: read A[buf1]m1;               gate VMCNT(0)
// RAW: each staged tile gated per-wave + shared barrier strictly before first
// read (P0-stage -> end-P1 gate+barrier -> P2 read; P2-stage -> end-P3 -> next-P0).
// WAR: buf staging starts >=1 barrier after its last read phase (P1 reads ->
// P2 stage; P3 reads -> next-P0 stage). Prologue stages tile0 + drain. Read/
// epilogue index formulas carried unchanged from the passing R20 kernel.
template<int BN, bool OUT_BF16>
__global__ __launch_bounds__(256, 2)
void gemm4p(const u16* __restrict__ A, const u16* __restrict__ Bt,
            float* __restrict__ Cf, u16* __restrict__ Cb, int N, int K, int gm) {
  constexpr int N_REP = BN / 32;        // 6 (BN=192) or 4 (BN=128)
  __shared__ alignas(16) u16 As[2][128 * 64];
  __shared__ alignas(16) u16 Bs[2][BN * 64];
  const int tid = threadIdx.x;
  const int lane = tid & 63;
  const int wid = tid >> 6;
  const int ql = lane & 15, kg = lane >> 4;
  const int wr = wid >> 1, wcn = wid & 1;

  const int nb = gridDim.x;
  const int b = blockIdx.x;
  const int swz = (b & 7) * (nb >> 3) + (b >> 3);
  const int m0 = (swz % gm) * 128;
  const int n0 = (swz / gm) * BN;

  const int srow = tid >> 3, schk = tid & 7;   // 32 rows x 8 chunks per call
  const u16* abase = A + (size_t)(m0 + srow) * K + schk * 8;
  const u16* bbase = Bt + (size_t)(n0 + srow) * K + schk * 8;

  auto stA = [&](int buf, int t, int c) {
    load_lds16(abase + (size_t)(c * 32) * K + t * 64,
               &As[buf][((c * 32 + srow) * 8 + schk) * 8]);
  };
  auto stB = [&](int buf, int t, int c) {
    load_lds16(bbase + (size_t)(c * 32) * K + t * 64,
               &Bs[buf][((c * 32 + srow) * 8 + schk) * 8]);
  };
  auto stageAll = [&](int buf, int t) {
    stA(buf, t, 0); stA(buf, t, 1); stA(buf, t, 2); stA(buf, t, 3);
    #pragma unroll
    for (int c = 0; c < N_REP; c++) stB(buf, t, c);
  };

  f32x4 acc[4][N_REP] = {};
  u16x8 af[2][2];
  u16x8 bfull[N_REP][2];
  const int NT = K / 64;

  // prologue: tile 0 -> buf0; drain; barrier
  stageAll(0, 0);
  VMCNT(0);
  __builtin_amdgcn_sched_barrier(0);
  __builtin_amdgcn_s_barrier();

  #pragma unroll 1
  for (int i = 0; i < NT / 2; i++) {
    #pragma unroll
    for (int p = 0; p < 4; p++) {
      const int mh = p & 1;        // m-half
      const int cbuf = p >> 1;     // buf0, buf0, buf1, buf1
      // top reads: A m-half always; B full at mh==0 (reused at mh==1)
      #pragma unroll
      for (int mi = 0; mi < 2; mi++)
        #pragma unroll
        for (int kk = 0; kk < 2; kk++) {
          int row = wr * 64 + mh * 32 + mi * 16 + ql;
          int ch = ((kk << 2) | kg) ^ (ql & 7);
          af[mi][kk] = *(const u16x8*)&As[cbuf][(row * 8 + ch) * 8];
        }
      if (mh == 0) {
        #pragma unroll
        for (int j = 0; j < N_REP; j++)
          #pragma unroll
          for (int kk = 0; kk < 2; kk++) {
            int R = wcn * (16 * N_REP) + j * 16 + ql;
            int ch = ((kk << 2) | kg) ^ (ql & 7);
            bfull[j][kk] = *(const u16x8*)&Bs[cbuf][(R * 8 + ch) * 8];
          }
      }
      // burst staging: P0 -> tile 2i+1 into buf1; P2 -> tile 2i+2 into buf0
      if (p == 0) {
        stageAll(1, 2 * i + 1);
      } else if (p == 2) {
        if (2 * i + 2 < NT) stageAll(0, 2 * i + 2);
      }
      // gates only at end-P1 / end-P3 (retire the burst issued 1.5 phases ago)
      if (mh == 1) VMCNT(0);
      __builtin_amdgcn_sched_barrier(0);
      __builtin_amdgcn_s_barrier();
      asm volatile("s_waitcnt lgkmcnt(0)" ::: "memory");
      __builtin_amdgcn_sched_barrier(0);
      __builtin_amdgcn_s_setprio(1);
      #pragma unroll
      for (int mi = 0; mi < 2; mi++)
        #pragma unroll
        for (int j = 0; j < N_REP; j++)
          #pragma unroll
          for (int kk = 0; kk < 2; kk++)
            acc[mh * 2 + mi][j] = mfma16(af[mi][kk], bfull[j][kk], acc[mh * 2 + mi][j]);
      __builtin_amdgcn_s_setprio(0);
      __builtin_amdgcn_sched_barrier(0);
      __builtin_amdgcn_s_barrier();
    }
  }

  #pragma unroll
  for (int a = 0; a < 4; a++) {
    #pragma unroll
    for (int j = 0; j < N_REP; j++) {
      int row0 = m0 + wr * 64 + (a >> 1) * 32 + (a & 1) * 16 + kg * 4;
      int col = n0 + wcn * (16 * N_REP) + j * 16 + ql;
      #pragma unroll
      for (int r = 0; r < 4; r++) {
        if constexpr (OUT_BF16)
          Cb[(size_t)(row0 + r) * N + col] = f2bf(acc[a][j][r]);
        else
          Cf[(size_t)(row0 + r) * N + col] = acc[a][j][r];
      }
    }
  }
}

// ---------------- flash attention, causal, GQA (g=4) — unchanged from R20 ----------
__global__ __launch_bounds__(256, 2)
void attn_k(const u16* __restrict__ qkv, const u16* __restrict__ kr,
            const u16* __restrict__ vt, const float2* __restrict__ tab,
            u16* __restrict__ out, float qscale) {
  __shared__ alignas(16) u16 Kls[2][64 * 128];
  __shared__ alignas(16) u16 Vls[2][128 * 64];
  __shared__ alignas(16) u16 Plds[4][16][72];
  const int tid = threadIdx.x;
  const int lane = tid & 63, wave = tid >> 6;
  const int ql = lane & 15, kg = lane >> 4;

  const int b = blockIdx.x;
  const int bswz = (b & 7) * 64 + (b >> 3);   // bijective on [0,512)
  const int h = bswz >> 4;                    // head 0..31 (XCD-clustered)
  const int bxx = bswz & 15;                  // wrap-pair index 0..15
  const int hk = h >> 2;

  const u16* kbase = kr + (size_t)hk * 128 + (size_t)(tid >> 4) * 1024 + (tid & 15) * 8;
  const u16* vbase = vt + (size_t)hk * 128 * 2048 + (size_t)(tid >> 3) * 2048 + (tid & 7) * 8;

  int cur = 0;
  #pragma unroll 1
  for (int half_idx = 0; half_idx < 2; half_idx++) {
    const int tile = half_idx ? (31 - bxx) : bxx;
    const int q0 = tile * 64;
    const int qw = q0 + wave * 16;
    const int nsteps = tile + 1;

    // ---- fused Q-RoPE ----
    u16x8 qf[4];
    {
      const u16* qsrc = qkv + (size_t)(qw + ql) * 6144 + h * 128;
      u16x8 qa[4];
      #pragma unroll
      for (int kk = 0; kk < 4; kk++)
        qa[kk] = *(const u16x8*)(qsrc + kk * 32 + kg * 8);
      const float2* trow = tab + (size_t)(qw + ql) * 64;
      #pragma unroll
      for (int pr = 0; pr < 2; pr++) {
        #pragma unroll
        for (int e = 0; e < 8; e++) {
          float2 cs = trow[pr * 32 + kg * 8 + e];
          float a = bf2f(qa[pr][e]);
          float bb = bf2f(qa[pr + 2][e]);
          qf[pr][e]     = f2bf((a * cs.x - bb * cs.y) * qscale);
          qf[pr + 2][e] = f2bf((a * cs.y + bb * cs.x) * qscale);
        }
      }
    }

    f32x4 acc[8] = {};
    float m_run = -3e38f, l_run = 0.f;

    __syncthreads();   // previous tile's readers done before restaging buf0
    cur = 0;
    #pragma unroll
    for (int r = 0; r < 4; r++)
      load_lds16(kbase + (size_t)r * 16 * 1024, &Kls[0][(r * 256 + tid) * 8]);
    #pragma unroll
    for (int r = 0; r < 4; r++)
      load_lds16(vbase + (size_t)r * 32 * 2048, &Vls[0][(r * 256 + tid) * 8]);

    #pragma unroll 1
    for (int t = 0; t < nsteps; t++) {
      const int s0 = t * 64;
      const bool last = (t == nsteps - 1);
      __syncthreads();  // drains buf[cur] staging; prev reads of buf[cur^1] done
      if (t + 1 < nsteps) {
        const u16* kn = kbase + (size_t)(s0 + 64) * 1024;
        #pragma unroll
        for (int r = 0; r < 4; r++)
          load_lds16(kn + (size_t)r * 16 * 1024, &Kls[cur ^ 1][(r * 256 + tid) * 8]);
        const u16* vn = vbase + (s0 + 64);
        #pragma unroll
        for (int r = 0; r < 4; r++)
          load_lds16(vn + (size_t)r * 32 * 2048, &Vls[cur ^ 1][(r * 256 + tid) * 8]);
      }
      f32x4 sc[4] = {};
      __builtin_amdgcn_s_setprio(1);
      #pragma unroll
      for (int sb = 0; sb < 4; sb++) {
        const u16* krow = &Kls[cur][(sb * 16 + ql) * 128];
        #pragma unroll
        for (int kk = 0; kk < 4; kk++) {
          u16x8 kf = *(const u16x8*)(krow + (((kk * 4 + kg) ^ (ql & 7)) * 8));
          sc[sb] = mfma16(kf, qf[kk], sc[sb]);
        }
      }
      __builtin_amdgcn_s_setprio(0);
      float mt;
      if (last) {
        const int qg = qw + ql;
        mt = -3e38f;
        #pragma unroll
        for (int sb = 0; sb < 4; sb++)
          #pragma unroll
          for (int r = 0; r < 4; r++) {
            int s = s0 + sb * 16 + kg * 4 + r;
            float v = (s > qg) ? -3e38f : sc[sb][r];
            sc[sb][r] = v;
            mt = fmaxf(mt, v);
          }
      } else {
        float a0 = fmaxf(sc[0][0], sc[0][1]), a1 = fmaxf(sc[0][2], sc[0][3]);
        float a2 = fmaxf(sc[1][0], sc[1][1]), a3 = fmaxf(sc[1][2], sc[1][3]);
        float a4 = fmaxf(sc[2][0], sc[2][1]), a5 = fmaxf(sc[2][2], sc[2][3]);
        float a6 = fmaxf(sc[3][0], sc[3][1]), a7 = fmaxf(sc[3][2], sc[3][3]);
        float b0 = fmaxf(a0, a1), b1 = fmaxf(a2, a3);
        float b2 = fmaxf(a4, a5), b3 = fmaxf(a6, a7);
        mt = fmaxf(fmaxf(b0, b1), fmaxf(b2, b3));
      }
      mt = fmaxf(mt, __shfl_xor(mt, 16, 64));
      mt = fmaxf(mt, __shfl_xor(mt, 32, 64));
      if (!__all(mt - m_run <= 11.5f)) {
        float m_new = fmaxf(m_run, mt);
        float fco = exp2f(m_run - m_new);
        float fr[4];
        #pragma unroll
        for (int r = 0; r < 4; r++) fr[r] = __shfl(fco, (lane & 48) | (kg * 4 + r), 64);
        #pragma unroll
        for (int db = 0; db < 8; db++)
          #pragma unroll
          for (int r = 0; r < 4; r++) acc[db][r] *= fr[r];
        l_run *= fco;
        m_run = m_new;
      }
      float rs = 0.f;
      #pragma unroll
      for (int sb = 0; sb < 4; sb++) {
        float e0 = exp2f(sc[sb][0] - m_run);
        float e1 = exp2f(sc[sb][1] - m_run);
        float e2 = exp2f(sc[sb][2] - m_run);
        float e3 = exp2f(sc[sb][3] - m_run);
        rs += (e0 + e1) + (e2 + e3);
        ushort4 pk;
        pk.x = f2bf_n(e0); pk.y = f2bf_n(e1);
        pk.z = f2bf_n(e2); pk.w = f2bf_n(e3);
        *(ushort4*)&Plds[wave][ql][sb * 16 + kg * 4] = pk;
      }
      rs += __shfl_xor(rs, 16, 64);
      rs += __shfl_xor(rs, 32, 64);
      l_run += rs;
      __builtin_amdgcn_s_setprio(1);
      #pragma unroll
      for (int hf = 0; hf < 2; hf++) {
        u16x8 pf = *(const u16x8*)&Plds[wave][ql][hf * 32 + kg * 8];
        #pragma unroll
        for (int db = 0; db < 8; db++) {
          u16x8 vf = *(const u16x8*)&Vls[cur][((db * 16 + ql) << 6) +
                                              (((hf * 4 + kg) ^ (ql & 7)) << 3)];
          acc[db] = mfma16(pf, vf, acc[db]);
        }
      }
      __builtin_amdgcn_s_setprio(0);
      cur ^= 1;
    }

    float linv[4];
    #pragma unroll
    for (int r = 0; r < 4; r++)
      linv[r] = 1.f / __shfl(l_run, (lane & 48) | (kg * 4 + r), 64);
    #pragma unroll
    for (int db = 0; db < 8; db++) {
      int d = db * 16 + ql;
      #pragma unroll
      for (int r = 0; r < 4; r++) {
        int q = qw + kg * 4 + r;
        int col = (h * 128 + d) ^ ((q & 7) << 3);
        out[(size_t)q * 4096 + col] = f2bf_n(acc[db][r] * linv[r]);
      }
    }
  }
}

// ---------------- launcher ----------------
extern "C" void kernel_launch(void* const* d_in, const int* in_sizes, int n_in,
                              void* d_out, int out_size, void* d_ws, size_t ws_size,
                              hipStream_t stream) {
  const float* x  = (const float*)d_in[0];
  const float* Wq = (const float*)d_in[1];
  const float* Wk = (const float*)d_in[2];
  const float* Wv = (const float*)d_in[3];
  const float* Wo = (const float*)d_in[4];
  const int* start = (const int*)d_in[5];

  const int L = 2048, HID = 4096, NH = 32, NKV = 8;
  const int NQ = 4096, NKVD = 1024, NF = 6144;

  char* ws = (char*)d_ws;
  size_t off = 0;
  auto alloc = [&](size_t bytes) {
    void* p = ws + off;
    off += (bytes + 255) & ~(size_t)255;
    return p;
  };
  u16* x_b   = (u16*)alloc((size_t)L * HID * 2);
  // Wq_t, Wk_t, Wv_t MUST be contiguous (fused GEMM reads them as one 6144-row Bt).
  u16* Wq_t  = (u16*)alloc((size_t)NQ * HID * 2);
  u16* Wk_t  = (u16*)alloc((size_t)NKVD * HID * 2);
  u16* Wv_t  = (u16*)alloc((size_t)NKVD * HID * 2);
  u16* Wo_t  = (u16*)alloc((size_t)HID * NQ * 2);
  u16* k_r   = (u16*)alloc((size_t)L * NKVD * 2);
  u16* vt_b  = (u16*)alloc((size_t)NKV * 128 * L * 2);
  float2* tab = (float2*)alloc((size_t)L * 64 * sizeof(float2));
  u16* qkv_b  = (u16*)d_out;   // fused QKV output; fully rewritten by out-proj
  u16* attn_b = Wq_t;          // reuse Wq^T region after the fused GEMM

  const float qscale = 0.08838834764831845f * 1.4426950408889634f;  // 1/sqrt(128)*log2(e)

  // conversions / transposes / table (all GEMM inputs pre-swizzled)
  cvt_f32_bf16_swz<<<(L * HID / 8 + 255) / 256, 256, 0, stream>>>(x, x_b, L * HID / 8);
  transpose_cvt<<<dim3(HID / 128, NQ / 32), 256, 0, stream>>>(Wq, Wq_t, HID, NQ);
  transpose_cvt2<<<dim3(HID / 128, 2 * NKVD / 32), 256, 0, stream>>>(Wk, Wv, Wk_t, Wv_t, HID, NKVD);
  transpose_cvt<<<dim3(NQ / 128, HID / 32), 256, 0, stream>>>(Wo, Wo_t, NQ, HID);
  rope_table_k<<<(L * 64 + 255) / 256, 256, 0, stream>>>(tab, start, L);

  // fused QKV projection: 4-phase, BM=128 x BN=192 tiles, grid 512 (2 blocks/CU)
  gemm4p<192, true><<<512, 256, 0, stream>>>(x_b, Wq_t, nullptr, qkv_b, NF, HID, 16);

  // RoPE: K only (chunk-swizzled); V transpose+swizzle; Q-RoPE fused into attn_k
  rope_apply_b<<<(L * NKV * 8 + 255) / 256, 256, 0, stream>>>(qkv_b, NF, NQ, k_r, tab, L * NKV * 8, NKV, 1.0f, 1);
  vtrans_k<<<dim3(L / 32, 32), 256, 0, stream>>>(qkv_b, vt_b);

  // attention (XCD-clustered head mapping; K and V via swizzled LDS path)
  attn_k<<<512, 256, 0, stream>>>(qkv_b, k_r, vt_b, tab, attn_b, qscale);

  // output projection: 4-phase, BM=128 x BN=128 tiles, grid 512 (2 blocks/CU)
  gemm4p<128, false><<<512, 256, 0, stream>>>(attn_b, Wo_t, (float*)d_out, nullptr, HID, NQ, 16);
}

// Round 22
// 309.595 us; speedup vs baseline: 1.0081x; 1.0081x over previous
//
#include <hip/hip_runtime.h>

typedef unsigned short u16;
typedef float f32x4 __attribute__((ext_vector_type(4)));
typedef __bf16 bf16x8 __attribute__((ext_vector_type(8)));
typedef u16 u16x8 __attribute__((ext_vector_type(8)));

#define VMCNT(n) asm volatile("s_waitcnt vmcnt(" #n ")" ::: "memory")

static __device__ __forceinline__ u16 f2bf(float f) {
  union { float f; unsigned u; } v; v.f = f;
  unsigned r = v.u + 0x7fffu + ((v.u >> 16) & 1u);  // RNE
  return (u16)(r >> 16);
}
static __device__ __forceinline__ u16 f2bf_n(float f) {
  __bf16 h = (__bf16)f;          // native cvt (RNE)
  return __builtin_bit_cast(u16, h);
}
static __device__ __forceinline__ float bf2f(u16 x) {
  union { unsigned u; float f; } v; v.u = (unsigned)x << 16; return v.f;
}

static __device__ __forceinline__ f32x4 mfma16(u16x8 a, u16x8 b, f32x4 c) {
  return __builtin_amdgcn_mfma_f32_16x16x32_bf16(
      __builtin_bit_cast(bf16x8, a), __builtin_bit_cast(bf16x8, b), c, 0, 0, 0);
}

static __device__ __forceinline__ void load_lds16(const void* g, void* l) {
  __builtin_amdgcn_global_load_lds(
      (const __attribute__((address_space(1))) void*)g,
      (__attribute__((address_space(3))) void*)l, 16, 0, 0);
}

// ---------------- f32 -> bf16, GEMM-A pre-swizzled (chunk c of row r at c^(r&7)) ----
__global__ void cvt_f32_bf16_swz(const float* __restrict__ in, u16* __restrict__ out, int n8) {
  int i = blockIdx.x * blockDim.x + threadIdx.x;
  if (i >= n8) return;
  int row = i >> 9;
  int j = i & 511;
  int jp = (j & ~7) | ((j & 7) ^ (row & 7));
  const float* src = in + (size_t)i * 8;
  u16x8 o;
  #pragma unroll
  for (int e = 0; e < 8; e++) o[e] = f2bf(src[e]);
  *(u16x8*)(out + ((size_t)row << 12) + jp * 8) = o;
}

// ------- transpose + convert: W[K][N] f32 -> Wt[N][K] bf16, pre-swizzled rows -------
__global__ __launch_bounds__(256)
void transpose_cvt(const float* __restrict__ W, u16* __restrict__ Wt, int K, int N) {
  __shared__ float tile[128][33];
  const int k0 = blockIdx.x * 128, n0 = blockIdx.y * 32;
  const int tr = threadIdx.x >> 3;         // 0..31
  const int tc4 = (threadIdx.x & 7) * 4;   // 0..28
  #pragma unroll
  for (int it = 0; it < 4; it++) {
    int kl = it * 32 + tr;
    float4 v = *(const float4*)&W[(size_t)(k0 + kl) * N + n0 + tc4];
    tile[kl][tc4] = v.x; tile[kl][tc4 + 1] = v.y;
    tile[kl][tc4 + 2] = v.z; tile[kl][tc4 + 3] = v.w;
  }
  __syncthreads();
  const int nl = threadIdx.x >> 4;         // 0..15
  const int dch = threadIdx.x & 15;        // dest 16B chunk 0..15
  #pragma unroll
  for (int it = 0; it < 2; it++) {
    int n = n0 + it * 16 + nl;
    int sch = (dch & 8) | ((dch & 7) ^ (n & 7));  // source chunk (involution)
    u16x8 o;
    #pragma unroll
    for (int e = 0; e < 8; e++) o[e] = f2bf(tile[sch * 8 + e][it * 16 + nl]);
    *(u16x8*)&Wt[(size_t)n * K + k0 + dch * 8] = o;
  }
}

// ---- merged Wk/Wv transpose (same math; one dispatch, branch on blockIdx.y) ----
__global__ __launch_bounds__(256)
void transpose_cvt2(const float* __restrict__ Wk, const float* __restrict__ Wv,
                    u16* __restrict__ Wkt, u16* __restrict__ Wvt, int K, int N) {
  __shared__ float tile[128][33];
  const int sel = blockIdx.y >= (unsigned)(N / 32);
  const int n0 = (blockIdx.y - (sel ? N / 32 : 0)) * 32;
  const float* W = sel ? Wv : Wk;
  u16* Wt = sel ? Wvt : Wkt;
  const int k0 = blockIdx.x * 128;
  const int tr = threadIdx.x >> 3;
  const int tc4 = (threadIdx.x & 7) * 4;
  #pragma unroll
  for (int it = 0; it < 4; it++) {
    int kl = it * 32 + tr;
    float4 v = *(const float4*)&W[(size_t)(k0 + kl) * N + n0 + tc4];
    tile[kl][tc4] = v.x; tile[kl][tc4 + 1] = v.y;
    tile[kl][tc4 + 2] = v.z; tile[kl][tc4 + 3] = v.w;
  }
  __syncthreads();
  const int nl = threadIdx.x >> 4;
  const int dch = threadIdx.x & 15;
  #pragma unroll
  for (int it = 0; it < 2; it++) {
    int n = n0 + it * 16 + nl;
    int sch = (dch & 8) | ((dch & 7) ^ (n & 7));
    u16x8 o;
    #pragma unroll
    for (int e = 0; e < 8; e++) o[e] = f2bf(tile[sch * 8 + e][it * 16 + nl]);
    *(u16x8*)&Wt[(size_t)n * K + k0 + dch * 8] = o;
  }
}

// ---------------- V transpose: qkv V cols -> vt[hk][d][s], chunk-swizzled ----------
__global__ __launch_bounds__(256)
void vtrans_k(const u16* __restrict__ qkv, u16* __restrict__ vt) {
  __shared__ u16 tile[32][33];
  int tx = threadIdx.x & 31, ty = threadIdx.x >> 5;
  int s0 = blockIdx.x * 32;
  int d0 = (blockIdx.y & 3) * 32;
  int hk = blockIdx.y >> 2;
  const u16* src = qkv + 5120 + (size_t)hk * 128;
  #pragma unroll
  for (int i = ty; i < 32; i += 8)
    tile[i][tx] = src[(size_t)(s0 + i) * 6144 + d0 + tx];
  __syncthreads();
  u16* dst = vt + (size_t)hk * 128 * 2048;
  #pragma unroll
  for (int i = ty; i < 32; i += 8) {
    int d = d0 + i;
    int s = s0 + tx;
    int sw = (s & ~63) | ((((s >> 3) & 7) ^ (d & 7)) << 3) | (s & 7);
    dst[(size_t)d * 2048 + sw] = tile[tx][i];
  }
}

// ---------------- RoPE cos/sin table: [L][64] float2 ----------------
__global__ void rope_table_k(float2* __restrict__ tab, const int* __restrict__ start, int L) {
  int i = blockIdx.x * blockDim.x + threadIdx.x;
  if (i >= L * 64) return;
  int p = i >> 6, j = i & 63;
  float inv = powf(10000.0f, -(float)j / 64.0f);
  float ang = (float)(p + start[0]) * inv;
  tab[i] = make_float2(cosf(ang), sinf(ang));
}

// ---------------- RoPE apply (bf16 in, strided) -> bf16 [L][H][128], * scale ----------
// (used for K only; Q-RoPE is fused into attn_k)
__global__ void rope_apply_b(const u16* __restrict__ in, int istride, int icol,
                             u16* __restrict__ outp, const float2* __restrict__ tab,
                             int total, int H, float scale, int swz) {
  int i = blockIdx.x * blockDim.x + threadIdx.x;  // total = L*H*8
  if (i >= total) return;
  int j8 = (i & 7) * 8;
  int h = (i >> 3) % H;
  int p = i / (8 * H);
  const u16* base = in + (size_t)p * istride + icol + h * 128;
  u16x8 a = *(const u16x8*)(base + j8);
  u16x8 b = *(const u16x8*)(base + j8 + 64);
  u16x8 o1, o2;
  #pragma unroll
  for (int e = 0; e < 8; e++) {
    float2 cs = tab[p * 64 + j8 + e];
    float av = bf2f(a[e]), bv = bf2f(b[e]);
    o1[e] = f2bf((av * cs.x - bv * cs.y) * scale);
    o2[e] = f2bf((av * cs.y + bv * cs.x) * scale);
  }
  int c1 = i & 7;
  int cs1 = swz ? (c1 ^ (p & 7)) : c1;
  u16* ob = outp + ((size_t)p * H + h) * 128 + cs1 * 8;
  *(u16x8*)ob = o1;
  *(u16x8*)(ob + 64) = o2;
}

// ======== 8-phase GEMM, 2 BLOCKS/CU, READ-BALANCED (R14/R20, best-measured) ========
template<int BN, bool OUT_BF16>
__global__ __launch_bounds__(256, 2)
void gemm8p(const u16* __restrict__ A, const u16* __restrict__ Bt,
            float* __restrict__ Cf, u16* __restrict__ Cb, int N, int K, int gm) {
  constexpr int N_REP = BN / 32;        // 6 (BN=192) or 4 (BN=128)
  constexpr int NHALF = N_REP / 2;      // 3 or 2
  __shared__ alignas(16) u16 As[2][128 * 64];
  __shared__ alignas(16) u16 Bs[2][BN * 64];
  const int tid = threadIdx.x;
  const int lane = tid & 63;
  const int wid = tid >> 6;
  const int ql = lane & 15, kg = lane >> 4;
  const int wr = wid >> 1, wcn = wid & 1;

  const int nb = gridDim.x;
  const int b = blockIdx.x;
  const int swz = (b & 7) * (nb >> 3) + (b >> 3);
  const int m0 = (swz % gm) * 128;
  const int n0 = (swz / gm) * BN;

  const int srow = tid >> 3, schk = tid & 7;   // 32 rows x 8 chunks per call
  const u16* abase = A + (size_t)(m0 + srow) * K + schk * 8;
  const u16* bbase = Bt + (size_t)(n0 + srow) * K + schk * 8;

  auto stA = [&](int buf, int t, int c) {
    load_lds16(abase + (size_t)(c * 32) * K + t * 64,
               &As[buf][((c * 32 + srow) * 8 + schk) * 8]);
  };
  auto stB = [&](int buf, int t, int c) {
    load_lds16(bbase + (size_t)(c * 32) * K + t * 64,
               &Bs[buf][((c * 32 + srow) * 8 + schk) * 8]);
  };

  f32x4 acc[4][N_REP] = {};
  u16x8 af[2][2];
  u16x8 bfr[NHALF][2];
  u16x8 bpre[NHALF][2];
  const int NT = K / 64;

  stA(0, 0, 0); stA(0, 0, 1); stA(0, 0, 2); stA(0, 0, 3);
  #pragma unroll
  for (int c = 0; c < BN / 32; c++) stB(0, 0, c);
  VMCNT(0);
  __builtin_amdgcn_sched_barrier(0);
  __builtin_amdgcn_s_barrier();
  #pragma unroll
  for (int ni = 0; ni < NHALF; ni++)
    #pragma unroll
    for (int kk = 0; kk < 2; kk++) {
      int R = wcn * (16 * N_REP) + ni * 16 + ql;
      int ch = ((kk << 2) | kg) ^ (ql & 7);
      bpre[ni][kk] = *(const u16x8*)&Bs[0][(R * 8 + ch) * 8];
    }

  #pragma unroll 1
  for (int i = 0; i < NT / 2; i++) {
    const bool tail = (i == NT / 2 - 1);
    #pragma unroll
    for (int p = 0; p < 8; p++) {
      const int q = p & 3;
      const int m = q >> 1, n2 = q & 1;
      const int cbuf = (p < 4) ? 0 : 1;
      if (q == 0 || q == 2) {
        #pragma unroll
        for (int mi = 0; mi < 2; mi++)
          #pragma unroll
          for (int kk = 0; kk < 2; kk++) {
            int row = wr * 64 + m * 32 + mi * 16 + ql;
            int ch = ((kk << 2) | kg) ^ (ql & 7);
            af[mi][kk] = *(const u16x8*)&As[cbuf][(row * 8 + ch) * 8];
          }
      }
      if (q == 1) {
        #pragma unroll
        for (int ni = 0; ni < NHALF; ni++)
          #pragma unroll
          for (int kk = 0; kk < 2; kk++) {
            int R = wcn * (16 * N_REP) + 16 * NHALF + ni * 16 + ql;
            int ch = ((kk << 2) | kg) ^ (ql & 7);
            bfr[ni][kk] = *(const u16x8*)&Bs[cbuf][(R * 8 + ch) * 8];
          }
      }
      const int st = 2 * i + 1 + (p >= 4 ? 1 : 0);
      const int sbuf = st & 1;
      if (st < NT) {
        if constexpr (BN == 192) {
          if (q == 0) { stA(sbuf, st, 0); stA(sbuf, st, 2); stB(sbuf, st, 0); }
          else if (q == 1) { stB(sbuf, st, 1); stB(sbuf, st, 3); stB(sbuf, st, 4); }
          else if (q == 2) { stB(sbuf, st, 2); stB(sbuf, st, 5); }
          else { stA(sbuf, st, 1); stA(sbuf, st, 3); }
        } else {
          if (q == 0) { stA(sbuf, st, 0); stA(sbuf, st, 2); stB(sbuf, st, 0); }
          else if (q == 1) { stB(sbuf, st, 2); stB(sbuf, st, 1); }
          else if (q == 2) { stB(sbuf, st, 3); }
          else { stA(sbuf, st, 1); stA(sbuf, st, 3); }
        }
      }
      if (!tail || p < 4) {
        if constexpr (BN == 192) {
          if (q == 1) VMCNT(6);
          else if (q == 3) VMCNT(4);
          else VMCNT(5);
        } else {
          if (q == 0 || q == 1) VMCNT(5);
          else VMCNT(3);
        }
      } else {
        if (p == 4) VMCNT(2);
        else VMCNT(0);
      }
      __builtin_amdgcn_sched_barrier(0);
      __builtin_amdgcn_s_barrier();
      asm volatile("s_waitcnt lgkmcnt(0)" ::: "memory");
      __builtin_amdgcn_sched_barrier(0);
      if (q == 3) {
        const int nbuf = (p == 3) ? 1 : 0;
        const bool valid = (p == 3) || (2 * i + 2 < NT);
        if (valid) {
          #pragma unroll
          for (int ni = 0; ni < NHALF; ni++)
            #pragma unroll
            for (int kk = 0; kk < 2; kk++) {
              int R = wcn * (16 * N_REP) + ni * 16 + ql;
              int ch = ((kk << 2) | kg) ^ (ql & 7);
              bpre[ni][kk] = *(const u16x8*)&Bs[nbuf][(R * 8 + ch) * 8];
            }
        }
      }
      __builtin_amdgcn_s_setprio(1);
      #pragma unroll
      for (int mi = 0; mi < 2; mi++)
        #pragma unroll
        for (int ni = 0; ni < NHALF; ni++)
          #pragma unroll
          for (int kk = 0; kk < 2; kk++) {
            if (n2 == 0)
              acc[m * 2 + mi][ni] = mfma16(af[mi][kk], bpre[ni][kk], acc[m * 2 + mi][ni]);
            else
              acc[m * 2 + mi][NHALF + ni] = mfma16(af[mi][kk], bfr[ni][kk], acc[m * 2 + mi][NHALF + ni]);
          }
      __builtin_amdgcn_s_setprio(0);
      __builtin_amdgcn_sched_barrier(0);
      __builtin_amdgcn_s_barrier();
    }
  }

  #pragma unroll
  for (int a = 0; a < 4; a++) {
    #pragma unroll
    for (int j = 0; j < N_REP; j++) {
      int row0 = m0 + wr * 64 + (a >> 1) * 32 + (a & 1) * 16 + kg * 4;
      int col = n0 + wcn * (16 * N_REP) + j * 16 + ql;
      #pragma unroll
      for (int r = 0; r < 4; r++) {
        if constexpr (OUT_BF16)
          Cb[(size_t)(row0 + r) * N + col] = f2bf(acc[a][j][r]);
        else
          Cf[(size_t)(row0 + r) * N + col] = acc[a][j][r];
      }
    }
  }
}

// ---------------- flash attention, causal, GQA (g=4) — R20 (best-measured) ----------
__global__ __launch_bounds__(256, 2)
void attn_k(const u16* __restrict__ qkv, const u16* __restrict__ kr,
            const u16* __restrict__ vt, const float2* __restrict__ tab,
            u16* __restrict__ out, float qscale) {
  __shared__ alignas(16) u16 Kls[2][64 * 128];
  __shared__ alignas(16) u16 Vls[2][128 * 64];
  __shared__ alignas(16) u16 Plds[4][16][72];
  const int tid = threadIdx.x;
  const int lane = tid & 63, wave = tid >> 6;
  const int ql = lane & 15, kg = lane >> 4;

  const int b = blockIdx.x;
  const int bswz = (b & 7) * 64 + (b >> 3);   // bijective on [0,512)
  const int h = bswz >> 4;                    // head 0..31 (XCD-clustered)
  const int bxx = bswz & 15;                  // wrap-pair index 0..15
  const int hk = h >> 2;

  const u16* kbase = kr + (size_t)hk * 128 + (size_t)(tid >> 4) * 1024 + (tid & 15) * 8;
  const u16* vbase = vt + (size_t)hk * 128 * 2048 + (size_t)(tid >> 3) * 2048 + (tid & 7) * 8;

  int cur = 0;
  #pragma unroll 1
  for (int half_idx = 0; half_idx < 2; half_idx++) {
    const int tile = half_idx ? (31 - bxx) : bxx;
    const int q0 = tile * 64;
    const int qw = q0 + wave * 16;
    const int nsteps = tile + 1;

    // ---- fused Q-RoPE ----
    u16x8 qf[4];
    {
      const u16* qsrc = qkv + (size_t)(qw + ql) * 6144 + h * 128;
      u16x8 qa[4];
      #pragma unroll
      for (int kk = 0; kk < 4; kk++)
        qa[kk] = *(const u16x8*)(qsrc + kk * 32 + kg * 8);
      const float2* trow = tab + (size_t)(qw + ql) * 64;
      #pragma unroll
      for (int pr = 0; pr < 2; pr++) {
        #pragma unroll
        for (int e = 0; e < 8; e++) {
          float2 cs = trow[pr * 32 + kg * 8 + e];
          float a = bf2f(qa[pr][e]);
          float bb = bf2f(qa[pr + 2][e]);
          qf[pr][e]     = f2bf((a * cs.x - bb * cs.y) * qscale);
          qf[pr + 2][e] = f2bf((a * cs.y + bb * cs.x) * qscale);
        }
      }
    }

    f32x4 acc[8] = {};
    float m_run = -3e38f, l_run = 0.f;

    __syncthreads();   // previous tile's readers done before restaging buf0
    cur = 0;
    #pragma unroll
    for (int r = 0; r < 4; r++)
      load_lds16(kbase + (size_t)r * 16 * 1024, &Kls[0][(r * 256 + tid) * 8]);
    #pragma unroll
    for (int r = 0; r < 4; r++)
      load_lds16(vbase + (size_t)r * 32 * 2048, &Vls[0][(r * 256 + tid) * 8]);

    #pragma unroll 1
    for (int t = 0; t < nsteps; t++) {
      const int s0 = t * 64;
      const bool last = (t == nsteps - 1);
      __syncthreads();  // drains buf[cur] staging; prev reads of buf[cur^1] done
      if (t + 1 < nsteps) {
        const u16* kn = kbase + (size_t)(s0 + 64) * 1024;
        #pragma unroll
        for (int r = 0; r < 4; r++)
          load_lds16(kn + (size_t)r * 16 * 1024, &Kls[cur ^ 1][(r * 256 + tid) * 8]);
        const u16* vn = vbase + (s0 + 64);
        #pragma unroll
        for (int r = 0; r < 4; r++)
          load_lds16(vn + (size_t)r * 32 * 2048, &Vls[cur ^ 1][(r * 256 + tid) * 8]);
      }
      f32x4 sc[4] = {};
      __builtin_amdgcn_s_setprio(1);
      #pragma unroll
      for (int sb = 0; sb < 4; sb++) {
        const u16* krow = &Kls[cur][(sb * 16 + ql) * 128];
        #pragma unroll
        for (int kk = 0; kk < 4; kk++) {
          u16x8 kf = *(const u16x8*)(krow + (((kk * 4 + kg) ^ (ql & 7)) * 8));
          sc[sb] = mfma16(kf, qf[kk], sc[sb]);
        }
      }
      __builtin_amdgcn_s_setprio(0);
      float mt;
      if (last) {
        const int qg = qw + ql;
        mt = -3e38f;
        #pragma unroll
        for (int sb = 0; sb < 4; sb++)
          #pragma unroll
          for (int r = 0; r < 4; r++) {
            int s = s0 + sb * 16 + kg * 4 + r;
            float v = (s > qg) ? -3e38f : sc[sb][r];
            sc[sb][r] = v;
            mt = fmaxf(mt, v);
          }
      } else {
        float a0 = fmaxf(sc[0][0], sc[0][1]), a1 = fmaxf(sc[0][2], sc[0][3]);
        float a2 = fmaxf(sc[1][0], sc[1][1]), a3 = fmaxf(sc[1][2], sc[1][3]);
        float a4 = fmaxf(sc[2][0], sc[2][1]), a5 = fmaxf(sc[2][2], sc[2][3]);
        float a6 = fmaxf(sc[3][0], sc[3][1]), a7 = fmaxf(sc[3][2], sc[3][3]);
        float b0 = fmaxf(a0, a1), b1 = fmaxf(a2, a3);
        float b2 = fmaxf(a4, a5), b3 = fmaxf(a6, a7);
        mt = fmaxf(fmaxf(b0, b1), fmaxf(b2, b3));
      }
      mt = fmaxf(mt, __shfl_xor(mt, 16, 64));
      mt = fmaxf(mt, __shfl_xor(mt, 32, 64));
      if (!__all(mt - m_run <= 11.5f)) {
        float m_new = fmaxf(m_run, mt);
        float fco = exp2f(m_run - m_new);
        float fr[4];
        #pragma unroll
        for (int r = 0; r < 4; r++) fr[r] = __shfl(fco, (lane & 48) | (kg * 4 + r), 64);
        #pragma unroll
        for (int db = 0; db < 8; db++)
          #pragma unroll
          for (int r = 0; r < 4; r++) acc[db][r] *= fr[r];
        l_run *= fco;
        m_run = m_new;
      }
      float rs = 0.f;
      #pragma unroll
      for (int sb = 0; sb < 4; sb++) {
        float e0 = exp2f(sc[sb][0] - m_run);
        float e1 = exp2f(sc[sb][1] - m_run);
        float e2 = exp2f(sc[sb][2] - m_run);
        float e3 = exp2f(sc[sb][3] - m_run);
        rs += (e0 + e1) + (e2 + e3);
        ushort4 pk;
        pk.x = f2bf_n(e0); pk.y = f2bf_n(e1);
        pk.z = f2bf_n(e2); pk.w = f2bf_n(e3);
        *(ushort4*)&Plds[wave][ql][sb * 16 + kg * 4] = pk;
      }
      rs += __shfl_xor(rs, 16, 64);
      rs += __shfl_xor(rs, 32, 64);
      l_run += rs;
      __builtin_amdgcn_s_setprio(1);
      #pragma unroll
      for (int hf = 0; hf < 2; hf++) {
        u16x8 pf = *(const u16x8*)&Plds[wave][ql][hf * 32 + kg * 8];
        #pragma unroll
        for (int db = 0; db < 8; db++) {
          u16x8 vf = *(const u16x8*)&Vls[cur][((db * 16 + ql) << 6) +
                                              (((hf * 4 + kg) ^ (ql & 7)) << 3)];
          acc[db] = mfma16(pf, vf, acc[db]);
        }
      }
      __builtin_amdgcn_s_setprio(0);
      cur ^= 1;
    }

    float linv[4];
    #pragma unroll
    for (int r = 0; r < 4; r++)
      linv[r] = 1.f / __shfl(l_run, (lane & 48) | (kg * 4 + r), 64);
    #pragma unroll
    for (int db = 0; db < 8; db++) {
      int d = db * 16 + ql;
      #pragma unroll
      for (int r = 0; r < 4; r++) {
        int q = qw + kg * 4 + r;
        int col = (h * 128 + d) ^ ((q & 7) << 3);
        out[(size_t)q * 4096 + col] = f2bf_n(acc[db][r] * linv[r]);
      }
    }
  }
}

// ---------------- launcher ----------------
extern "C" void kernel_launch(void* const* d_in, const int* in_sizes, int n_in,
                              void* d_out, int out_size, void* d_ws, size_t ws_size,
                              hipStream_t stream) {
  const float* x  = (const float*)d_in[0];
  const float* Wq = (const float*)d_in[1];
  const float* Wk = (const float*)d_in[2];
  const float* Wv = (const float*)d_in[3];
  const float* Wo = (const float*)d_in[4];
  const int* start = (const int*)d_in[5];

  const int L = 2048, HID = 4096, NH = 32, NKV = 8;
  const int NQ = 4096, NKVD = 1024, NF = 6144;

  char* ws = (char*)d_ws;
  size_t off = 0;
  auto alloc = [&](size_t bytes) {
    void* p = ws + off;
    off += (bytes + 255) & ~(size_t)255;
    return p;
  };
  u16* x_b   = (u16*)alloc((size_t)L * HID * 2);
  // Wq_t, Wk_t, Wv_t MUST be contiguous (fused GEMM reads them as one 6144-row Bt).
  u16* Wq_t  = (u16*)alloc((size_t)NQ * HID * 2);
  u16* Wk_t  = (u16*)alloc((size_t)NKVD * HID * 2);
  u16* Wv_t  = (u16*)alloc((size_t)NKVD * HID * 2);
  u16* Wo_t  = (u16*)alloc((size_t)HID * NQ * 2);
  u16* k_r   = (u16*)alloc((size_t)L * NKVD * 2);
  u16* vt_b  = (u16*)alloc((size_t)NKV * 128 * L * 2);
  float2* tab = (float2*)alloc((size_t)L * 64 * sizeof(float2));
  u16* qkv_b  = (u16*)d_out;   // fused QKV output; fully rewritten by out-proj
  u16* attn_b = Wq_t;          // reuse Wq^T region after the fused GEMM

  const float qscale = 0.08838834764831845f * 1.4426950408889634f;  // 1/sqrt(128)*log2(e)

  // conversions / transposes / table (all GEMM inputs pre-swizzled)
  cvt_f32_bf16_swz<<<(L * HID / 8 + 255) / 256, 256, 0, stream>>>(x, x_b, L * HID / 8);
  transpose_cvt<<<dim3(HID / 128, NQ / 32), 256, 0, stream>>>(Wq, Wq_t, HID, NQ);
  transpose_cvt2<<<dim3(HID / 128, 2 * NKVD / 32), 256, 0, stream>>>(Wk, Wv, Wk_t, Wv_t, HID, NKVD);
  transpose_cvt<<<dim3(NQ / 128, HID / 32), 256, 0, stream>>>(Wo, Wo_t, NQ, HID);
  rope_table_k<<<(L * 64 + 255) / 256, 256, 0, stream>>>(tab, start, L);

  // fused QKV projection: BM=128 x BN=192 tiles, grid 512 (2 blocks/CU)
  gemm8p<192, true><<<512, 256, 0, stream>>>(x_b, Wq_t, nullptr, qkv_b, NF, HID, 16);

  // RoPE: K only (chunk-swizzled); V transpose+swizzle; Q-RoPE fused into attn_k
  rope_apply_b<<<(L * NKV * 8 + 255) / 256, 256, 0, stream>>>(qkv_b, NF, NQ, k_r, tab, L * NKV * 8, NKV, 1.0f, 1);
  vtrans_k<<<dim3(L / 32, 32), 256, 0, stream>>>(qkv_b, vt_b);

  // attention (XCD-clustered head mapping; K and V via swizzled LDS path)
  attn_k<<<512, 256, 0, stream>>>(qkv_b, k_r, vt_b, tab, attn_b, qscale);

  // output projection: BM=128 x BN=128 tiles, grid 512 (2 blocks/CU)
  gemm8p<128, false><<<512, 256, 0, stream>>>(attn_b, Wo_t, (float*)d_out, nullptr, HID, NQ, 16);
}